// Round 1
// baseline (3047.421 us; speedup 1.0000x reference)
//
#include <hip/hip_runtime.h>

// KanvolutionLayer: out[b,o,hw] = (sum_{p,c} x^(p+1) Wp[p,o,c] + bp[o]) / (1 + |sum_{q,c} x^(q+1) Wq[q,o,c]|)
// MFMA GEMM, M=100352 (b*hw), K=1280 (p*256+c), N=512 (p/q outs interleaved per 16).
// R4 (prev): A in regs (xv/pw/xn), hi+lo staged to 64KB LDS -> 2 blocks/CU, MfmaUtil 33%,
//   Occupancy 20%, all BW far under ceiling => latency/occupancy-bound.
// R5: 3 blocks/CU.
//  - LDS 64->52.1KB: stage hi slabs only (p0-3 full 8KB @ p*8192; p4 halved to p-cols, 4KB @32768).
//    lo (p1-4) direct from L2 via wl[ni] pointers, prefetched one p-step ahead into bl[4].
//  - regs ~200 -> ~155: drop xv/xn; x tile (32c x 128m, row stride 129 floats for bank spread)
//    DMA-staged to LDS @36864 with the W slabs; pw init/update re-read x from LDS (volatile
//    blocks CSE back into a 32-reg xv). p-block restructured mi-outer so only one ah/al live.
//  - launch_bounds(256,3); bijective XCD swizzle (3136%8==0) so 4 nt-siblings share an XCD L2.

typedef __attribute__((ext_vector_type(8))) short bf16x8;           // MFMA A/B frag (4 VGPRs)
typedef __attribute__((ext_vector_type(4))) float f32x4;            // MFMA C/D frag

#define CIN    256
#define HW3    3136          // 56*56
#define MTOT   100352        // 32*3136 = 784 * 128
#define KTOT   1280
#define WPLANE (512 * 1280)

#define XOFF   36864                 // LDS offset of x tile (after 4*8192 + 4096 W slabs)
#define XSTR   516                   // x row stride bytes = 129 floats (breaks quad-bank aliasing)
#define LDSSZ  (XOFF + 32 * XSTR)    // 53376 B -> 3 blocks/CU (3*53376 = 160128 <= 163840)

__device__ __forceinline__ unsigned short f2bf(float f) {
    union { float f; unsigned int u; } cv; cv.f = f;
    unsigned int u = cv.u;
    return (unsigned short)((u + 0x7FFFu + ((u >> 16) & 1u)) >> 16);  // RNE
}
__device__ __forceinline__ float bf2f(unsigned short h) {
    union { unsigned int u; float f; } cv; cv.u = ((unsigned int)h) << 16;
    return cv.f;
}

// Pack weights into bf16 hi/lo planes [512][1280]; row n -> (o,isq):
//   o = (n>>5)*16 + (n&15), isq = (n>>4)&1  (pairs P/Q frags per 16 cols). k = p*256 + c.
__global__ void pack_w_kernel(const float* __restrict__ Wp,
                              const float* __restrict__ Wq,
                              unsigned short* __restrict__ Whi,
                              unsigned short* __restrict__ Wlo) {
    int idx = blockIdx.x * 256 + threadIdx.x;      // [0, 512*1280)
    int n = idx / KTOT;
    int k = idx - n * KTOT;
    int p = k >> 8, c = k & 255;
    int o = ((n >> 5) << 4) + (n & 15);
    int isq = (n >> 4) & 1;
    float v;
    if (isq) v = (p < 4) ? Wq[((size_t)p * 256 + o) * 256 + c] : 0.0f;
    else     v = Wp[((size_t)p * 256 + o) * 256 + c];
    unsigned short h = f2bf(v);
    Whi[idx] = h;
    Wlo[idx] = f2bf(v - bf2f(h));   // exact residual, then one rounding
}

// Pack top-16 bits of 8 fp32 into a bf16x8 frag (truncation) via v_perm_b32.
__device__ __forceinline__ bf16x8 pack_hi8(const float* v) {
    const unsigned int* u = (const unsigned int*)v;
    union { unsigned int w[4]; bf16x8 h; } r;
    r.w[0] = __builtin_amdgcn_perm(u[1], u[0], 0x07060302);
    r.w[1] = __builtin_amdgcn_perm(u[3], u[2], 0x07060302);
    r.w[2] = __builtin_amdgcn_perm(u[5], u[4], 0x07060302);
    r.w[3] = __builtin_amdgcn_perm(u[7], u[6], 0x07060302);
    return r.h;
}
__device__ __forceinline__ void resid8(const float* v, float* l) {
#pragma unroll
    for (int j = 0; j < 8; ++j) {
        union { unsigned int u; float f; } cv;
        cv.u = ((const unsigned int*)v)[j] & 0xFFFF0000u;    // hi as fp32 (exact)
        l[j] = v[j] - cv.f;                                  // exact residual
    }
}

__global__ __launch_bounds__(256, 3) void kanv_gemm(
    const float* __restrict__ x,
    const unsigned short* __restrict__ Whi,
    const unsigned short* __restrict__ Wlo,
    const float* __restrict__ bp,
    float* __restrict__ out)
{
    __shared__ __align__(16) char sB[LDSSZ];

    const int tid  = threadIdx.x;
    const int lane = tid & 63;
    const int wave = tid >> 6;
    const int wm   = wave >> 1;
    const int wn   = wave & 1;
    const int col  = lane & 15;
    const int quad = lane >> 4;

    // XCD swizzle: grid=3136=8*392; bids ==k (mod 8) land on XCD k and get a contiguous
    // orig range -> all 4 nt-siblings of an mt share one XCD's L2 (x panel reuse).
    const int bid  = blockIdx.x;
    const int orig = (bid & 7) * 392 + (bid >> 3);   // bijective
    const int nt = orig & 3;                          // n-tile (4 x 128 = 512)
    const int mt = orig >> 2;                         // m-tile (784 x 128)
    const int m0 = mt * 128 + wm * 64;

    // lo-plane direct pointers: n = nt*128 + wn*64 + ni*16 + col; frag at + p*256 + g*32
    const unsigned short* wl[4];
#pragma unroll
    for (int ni = 0; ni < 4; ++ni) {
        int n = nt * 128 + wn * 64 + ni * 16 + col;
        wl[ni] = Wlo + (size_t)n * KTOT + quad * 8;
    }

    // ---- W-hi staging geometry (slabs 0..3 full) ----
    // chunk t = i*64 + lane (i = wave + 4*ii): n = i*16 + col, c4 = quad
    //   src = plane + (nt*128+n)*2560B + (p*256+g*32)*2B + c4*16B ; dst = s*8192 + i*1024 + lane*16
    int voff[2];
#pragma unroll
    for (int ii = 0; ii < 2; ++ii) {
        int i = wave + 4 * ii;
        voff[ii] = (nt * 128 + i * 16 + col) * 2560 + quad * 16;   // bytes
    }
    // slab4 (p-cols only: n with (n>>4)&1==0, i.e. n = i*32 + col, i=0..3): 1 chunk per wave
    const int voff4 = (nt * 128 + wave * 32 + col) * 2560 + quad * 16;

    // ---- x staging geometry ----
    // 64 chunks/g (32 c-rows x 2 halves of 64 m); 16 per wave. m-halves are 64-aligned and
    // HW3 = 49*64, so a 64-m chunk never crosses an image boundary.
    const int mb = mt * 128;
    const int b0 = mb / HW3, h0 = mb - b0 * HW3;
    int h1 = h0 + 64, b1 = b0;
    if (h1 >= HW3) { h1 -= HW3; b1 += 1; }
    const float* xh0 = x + (size_t)b0 * CIN * HW3 + h0 + lane;   // per-lane src
    const float* xh1 = x + (size_t)b1 * CIN * HW3 + h1 + lane;

    // x LDS read base: value(mi,j) at XOFF + (quad*8+j)*XSTR + (wm*64 + mi*16 + col)*4
    const char* xrb = sB + XOFF + quad * 8 * XSTR + (wm * 64 + col) * 4;

    f32x4 acc[4][4];
#pragma unroll
    for (int mi = 0; mi < 4; ++mi)
#pragma unroll
        for (int ni = 0; ni < 4; ++ni)
            acc[mi][ni] = (f32x4){0.f, 0.f, 0.f, 0.f};

    float pw[4][8];

    for (int g = 0; g < 8; ++g) {
        __syncthreads();   // prior g's sB reads complete before overwrite

        // ---- stage W-hi slabs 0..3 (8 instr/wave) ----
#pragma unroll
        for (int s = 0; s < 4; ++s) {
            const char* srcb = (const char*)Whi + (size_t)((s * 256 + g * 32) * 2);
#pragma unroll
            for (int ii = 0; ii < 2; ++ii) {
                const int i = wave + 4 * ii;
                __builtin_amdgcn_global_load_lds(
                    (const __attribute__((address_space(1))) void*)(srcb + voff[ii]),
                    (__attribute__((address_space(3))) void*)(sB + s * 8192 + i * 1024),
                    16, 0, 0);
            }
        }
        // slab4: p=4 hi, p-cols only (1 instr/wave)
        __builtin_amdgcn_global_load_lds(
            (const __attribute__((address_space(1))) void*)((const char*)Whi + (4 * 256 + g * 32) * 2 + voff4),
            (__attribute__((address_space(3))) void*)(sB + 32768 + wave * 1024),
            16, 0, 0);
        // x tile: 16 chunks/wave, 4B/lane DMA (row stride 129 floats -> pad untouched)
#pragma unroll
        for (int i = 0; i < 16; ++i) {
            const int cl = wave * 8 + (i >> 1);                    // c-row in tile
            const float* src = ((i & 1) ? xh1 : xh0) + (size_t)(g * 32 + cl) * HW3;
            __builtin_amdgcn_global_load_lds(
                (const __attribute__((address_space(1))) void*)src,
                (__attribute__((address_space(3))) void*)(sB + XOFF + cl * XSTR + (i & 1) * 256),
                4, 0, 0);
        }
        __syncthreads();   // compiler drains vmcnt before barrier -> DMA visible to all waves

        // ---- prefetch lo frags for p=1 (direct from L2) ----
        bf16x8 bl[4];
#pragma unroll
        for (int ni = 0; ni < 4; ++ni)
            bl[ni] = *(const bf16x8*)(wl[ni] + 1 * 256 + g * 32);

        // ---- init pw = x from LDS (volatile: keep as loads, not a live xv array) ----
#pragma unroll
        for (int mi = 0; mi < 4; ++mi)
#pragma unroll
            for (int j = 0; j < 8; ++j)
                pw[mi][j] = *(const volatile float*)(xrb + j * XSTR + mi * 64);

        // ---- compute 5 p-chunks: A packed from pw regs, B-hi from LDS, B-lo from bl regs ----
#pragma unroll
        for (int p = 0; p < 5; ++p) {
            bf16x8 bh[4];
#pragma unroll
            for (int ni = 0; ni < 4; ++ni) {
                if (p == 4 && (ni & 1)) continue;                  // q-weights zero at p=4
                const char* ba = (p < 4)
                    ? (sB + p * 8192 + (wn * 4 + ni) * 1024 + quad * 256 + col * 16)
                    : (sB + 32768 + (wn * 2 + (ni >> 1)) * 1024 + quad * 256 + col * 16);
                bh[ni] = *(const bf16x8*)ba;
            }
#pragma unroll
            for (int mi = 0; mi < 4; ++mi) {
                bf16x8 ah = pack_hi8(pw[mi]);
                bf16x8 al;
                if (p > 0) {
                    float lo8[8];
                    resid8(pw[mi], lo8);
                    al = pack_hi8(lo8);
                }
#pragma unroll
                for (int ni = 0; ni < 4; ++ni) {
                    if (p == 4 && (ni & 1)) continue;
                    acc[mi][ni] = __builtin_amdgcn_mfma_f32_16x16x32_bf16(ah, bh[ni], acc[mi][ni], 0, 0, 0);
                    if (p > 0) {
                        acc[mi][ni] = __builtin_amdgcn_mfma_f32_16x16x32_bf16(al, bh[ni], acc[mi][ni], 0, 0, 0);
                        acc[mi][ni] = __builtin_amdgcn_mfma_f32_16x16x32_bf16(ah, bl[ni], acc[mi][ni], 0, 0, 0);
                    }
                }
            }
            if (p < 4) {
                // issue lo loads for p+1 now (~L2 latency covered by pw update + next pack + hi MFMAs)
#pragma unroll
                for (int ni = 0; ni < 4; ++ni) {
                    if (p + 1 == 4 && (ni & 1)) continue;
                    bl[ni] = *(const bf16x8*)(wl[ni] + (p + 1) * 256 + g * 32);
                }
                // next power, fp32 (x re-read from LDS; volatile blocks CSE into an xv array)
#pragma unroll
                for (int mi = 0; mi < 4; ++mi)
#pragma unroll
                    for (int j = 0; j < 8; ++j)
                        pw[mi][j] *= *(const volatile float*)(xrb + j * XSTR + mi * 64);
            }
        }
    }

    // ---- epilogue (verified R2/R3): pair (sum_p, sum_q) frags, bias, divide, float4 store ----
#pragma unroll
    for (int j = 0; j < 2; ++j) {
        const int o = (nt * 4 + wn * 2 + j) * 16 + col;
        const float bias = bp[o];
#pragma unroll
        for (int mi = 0; mi < 4; ++mi) {
            f32x4 sp = acc[mi][2 * j];
            f32x4 sq = acc[mi][2 * j + 1];
            const int mrow = m0 + mi * 16 + quad * 4;  // 4 consecutive hw, same image
            const int b2  = mrow / HW3;
            const int hw2 = mrow - b2 * HW3;
            float4 v;
            v.x = (sp[0] + bias) / (1.0f + fabsf(sq[0]));
            v.y = (sp[1] + bias) / (1.0f + fabsf(sq[1]));
            v.z = (sp[2] + bias) / (1.0f + fabsf(sq[2]));
            v.w = (sp[3] + bias) / (1.0f + fabsf(sq[3]));
            *(float4*)&out[((size_t)b2 * 256 + o) * HW3 + hw2] = v;
        }
    }
}

extern "C" void kernel_launch(void* const* d_in, const int* in_sizes, int n_in,
                              void* d_out, int out_size, void* d_ws, size_t ws_size,
                              hipStream_t stream) {
    const float* x  = (const float*)d_in[0];
    const float* Wp = (const float*)d_in[1];
    const float* bp = (const float*)d_in[2];
    const float* Wq = (const float*)d_in[3];
    float* out = (float*)d_out;
    unsigned short* Whi = (unsigned short*)d_ws;              // 1.31 MB
    unsigned short* Wlo = Whi + WPLANE;                        // +1.31 MB

    pack_w_kernel<<<WPLANE / 256, 256, 0, stream>>>(Wp, Wq, Whi, Wlo);
    kanv_gemm<<<(MTOT / 128) * 4, 256, 0, stream>>>(x, Whi, Wlo, bp, out);
}

// Round 2
// 466.813 us; speedup vs baseline: 6.5281x; 6.5281x over previous
//
#include <hip/hip_runtime.h>

// KanvolutionLayer: out[b,o,hw] = (sum_{p,c} x^(p+1) Wp[p,o,c] + bp[o]) / (1 + |sum_{q,c} x^(q+1) Wq[q,o,c]|)
// MFMA GEMM, M=100352 (b*hw), K=1280 (p*256+c), N=512 (p/q outs interleaved per 16).
// R4: 128x128 block, 64x64/wave, A in regs, 64KB LDS -> 2 blocks/CU (regs ~192 total AND LDS),
//     MfmaUtil 33%, latency-bound. 401 us.
// R5: LDS x-tile + volatile + mi-outer -> compiler spilled acc to scratch (WRITE 3.5GB, VGPR 84,
//     MfmaUtil 1-4%). Lesson: total unified regfile (arch+acc) is the occupancy limiter; shrink
//     the per-wave tile, don't fight the allocator.
// R6: 128x64 block (grid 784x8), 4 waves on m, 32x64/wave: acc[2][4]=32, xv/pw/xn=48 ->
//     ~135-150 total regs -> 3 waves/SIMD (launch_bounds(256,3), ~20-reg headroom).
//     B panel halves: ALL slabs staged (hi p0-4 + lo p1-4 = 9 x 4KB = 36KB LDS), no direct-L2
//     lo path. 3 blocks/CU; each SIMD hosts waves of 3 independent blocks -> barrier phases
//     overlap across blocks. XCD swizzle: 6272 = 8*784, 8 nt-siblings share an XCD L2 x panel.

typedef __attribute__((ext_vector_type(8))) short bf16x8;           // MFMA A/B frag (4 VGPRs)
typedef __attribute__((ext_vector_type(4))) float f32x4;            // MFMA C/D frag

#define CIN    256
#define HW3    3136          // 56*56
#define MTOT   100352        // 32*3136 = 784 * 128
#define KTOT   1280
#define WPLANE (512 * 1280)

__device__ __forceinline__ unsigned short f2bf(float f) {
    union { float f; unsigned int u; } cv; cv.f = f;
    unsigned int u = cv.u;
    return (unsigned short)((u + 0x7FFFu + ((u >> 16) & 1u)) >> 16);  // RNE
}
__device__ __forceinline__ float bf2f(unsigned short h) {
    union { unsigned int u; float f; } cv; cv.u = ((unsigned int)h) << 16;
    return cv.f;
}

// Pack weights into bf16 hi/lo planes [512][1280]; row n -> (o,isq):
//   o = (n>>5)*16 + (n&15), isq = (n>>4)&1  (pairs P/Q frags per 16 cols). k = p*256 + c.
__global__ void pack_w_kernel(const float* __restrict__ Wp,
                              const float* __restrict__ Wq,
                              unsigned short* __restrict__ Whi,
                              unsigned short* __restrict__ Wlo) {
    int idx = blockIdx.x * 256 + threadIdx.x;      // [0, 512*1280)
    int n = idx / KTOT;
    int k = idx - n * KTOT;
    int p = k >> 8, c = k & 255;
    int o = ((n >> 5) << 4) + (n & 15);
    int isq = (n >> 4) & 1;
    float v;
    if (isq) v = (p < 4) ? Wq[((size_t)p * 256 + o) * 256 + c] : 0.0f;
    else     v = Wp[((size_t)p * 256 + o) * 256 + c];
    unsigned short h = f2bf(v);
    Whi[idx] = h;
    Wlo[idx] = f2bf(v - bf2f(h));   // exact residual, then one rounding
}

// Pack top-16 bits of 8 fp32 into a bf16x8 frag (truncation) via v_perm_b32.
__device__ __forceinline__ bf16x8 pack_hi8(const float* v) {
    const unsigned int* u = (const unsigned int*)v;
    union { unsigned int w[4]; bf16x8 h; } r;
    r.w[0] = __builtin_amdgcn_perm(u[1], u[0], 0x07060302);
    r.w[1] = __builtin_amdgcn_perm(u[3], u[2], 0x07060302);
    r.w[2] = __builtin_amdgcn_perm(u[5], u[4], 0x07060302);
    r.w[3] = __builtin_amdgcn_perm(u[7], u[6], 0x07060302);
    return r.h;
}
__device__ __forceinline__ void resid8(const float* v, float* l) {
#pragma unroll
    for (int j = 0; j < 8; ++j) {
        union { unsigned int u; float f; } cv;
        cv.u = ((const unsigned int*)v)[j] & 0xFFFF0000u;    // hi as fp32 (exact)
        l[j] = v[j] - cv.f;                                  // exact residual
    }
}

__global__ __launch_bounds__(256, 3) void kanv_gemm(
    const float* __restrict__ x,
    const unsigned short* __restrict__ Whi,
    const unsigned short* __restrict__ Wlo,
    const float* __restrict__ bp,
    float* __restrict__ out)
{
    // 9 slabs x 4KB: s=0..4 -> hi p=s ; s=5..8 -> lo p=s-4. 36 KB total.
    __shared__ __align__(16) char sB[9 * 4096];

    const int tid  = threadIdx.x;
    const int lane = tid & 63;
    const int wave = tid >> 6;        // wave = wm (all 4 waves stack on m)
    const int col  = lane & 15;
    const int quad = lane >> 4;

    // XCD swizzle: grid=6272=8*784; bids ==k (mod 8) land on XCD k with contiguous orig range
    // -> all 8 nt-siblings of an mt share one XCD's L2 (x panel reuse).
    const int bid  = blockIdx.x;
    const int orig = (bid & 7) * 784 + (bid >> 3);   // bijective
    const int nt = orig & 7;                          // n-tile (8 x 64 = 512)
    const int mt = orig >> 3;                         // m-tile (784 x 128)
    const int m0 = mt * 128 + wave * 32;

    // per-mi x base: lane holds A[m = m0+mi*16+col][c = g*32+quad*8+j]
    const float* xb[2];
#pragma unroll
    for (int mi = 0; mi < 2; ++mi) {
        int m  = m0 + mi * 16 + col;
        int bb = m / HW3, hw = m - bb * HW3;
        xb[mi] = x + ((size_t)bb * CIN) * HW3 + hw;
    }

    // ---- staging geometry ----
    // slab = 64 rows (n-local) x 32 ch x 2B = 4KB = 4 wave-instructions, i = wave.
    // chunk t = wave*64 + lane: n-local = wave*16 + col, c4 = quad.
    //   src = plane + (nt*64 + n_local)*2560B + (p*256+g*32)*2B + quad*16B
    //   dst = sB + s*4096 + wave*1024 + lane*16  (DMA: uniform base + lane*16)
    const int voff = (nt * 64 + wave * 16 + col) * 2560 + quad * 16;   // bytes

    // frag-read base: addr = s*4096 + ni*1024 + quad*256 + col*16
    const int rbase = quad * 256 + col * 16;

    f32x4 acc[2][4];
#pragma unroll
    for (int mi = 0; mi < 2; ++mi)
#pragma unroll
        for (int ni = 0; ni < 4; ++ni)
            acc[mi][ni] = (f32x4){0.f, 0.f, 0.f, 0.f};

    float xv[2][8], pw[2][8], xn[2][8];

    // initial x load (g=0)
#pragma unroll
    for (int mi = 0; mi < 2; ++mi) {
        const float* xp = xb[mi] + (size_t)(quad * 8) * HW3;
#pragma unroll
        for (int j = 0; j < 8; ++j) { xv[mi][j] = xp[(size_t)j * HW3]; pw[mi][j] = xv[mi][j]; }
    }

    for (int g = 0; g < 8; ++g) {
        __syncthreads();   // prior g's sB reads complete before overwrite

        // ---- stage B slabs for this g (async DMA, 9 instr/wave) ----
#pragma unroll
        for (int s = 0; s < 9; ++s) {
            const unsigned short* plane = (s < 5) ? Whi : Wlo;
            const int p = (s < 5) ? s : (s - 4);
            const char* srcb = (const char*)plane + (size_t)((p * 256 + g * 32) * 2);
            __builtin_amdgcn_global_load_lds(
                (const __attribute__((address_space(1))) void*)(srcb + voff),
                (__attribute__((address_space(3))) void*)(sB + s * 4096 + wave * 1024),
                16, 0, 0);
        }
        __syncthreads();   // compiler drains vmcnt before barrier -> DMA visible to all waves

        // ---- prefetch x for g+1 (consumed ~5 chunks later) ----
        if (g < 7) {
#pragma unroll
            for (int mi = 0; mi < 2; ++mi) {
                const float* xp = xb[mi] + (size_t)((g + 1) * 32 + quad * 8) * HW3;
#pragma unroll
                for (int j = 0; j < 8; ++j) xn[mi][j] = xp[(size_t)j * HW3];
            }
        }

        // ---- compute 5 p-chunks from registers(A) + LDS(B) ----
#pragma unroll
        for (int p = 0; p < 5; ++p) {
            bf16x8 ah[2], al[2];
#pragma unroll
            for (int mi = 0; mi < 2; ++mi) {
                ah[mi] = pack_hi8(pw[mi]);
                if (p > 0) {
                    float lo[8];
                    resid8(pw[mi], lo);
                    al[mi] = pack_hi8(lo);
                }
            }
            const char* sb_p = sB + p * 4096 + rbase;
#pragma unroll
            for (int ni = 0; ni < 4; ++ni) {
                if (p == 4 && (ni & 1)) continue;            // q-weights zero at p=4
                bf16x8 bh = *(const bf16x8*)(sb_p + ni * 1024);
#pragma unroll
                for (int mi = 0; mi < 2; ++mi)
                    acc[mi][ni] = __builtin_amdgcn_mfma_f32_16x16x32_bf16(ah[mi], bh, acc[mi][ni], 0, 0, 0);
                if (p > 0) {
                    bf16x8 bl = *(const bf16x8*)(sB + (p + 4) * 4096 + rbase + ni * 1024);
#pragma unroll
                    for (int mi = 0; mi < 2; ++mi) {
                        acc[mi][ni] = __builtin_amdgcn_mfma_f32_16x16x32_bf16(al[mi], bh, acc[mi][ni], 0, 0, 0);
                        acc[mi][ni] = __builtin_amdgcn_mfma_f32_16x16x32_bf16(ah[mi], bl, acc[mi][ni], 0, 0, 0);
                    }
                }
            }
            if (p < 4) {
#pragma unroll
                for (int mi = 0; mi < 2; ++mi)
#pragma unroll
                    for (int j = 0; j < 8; ++j) pw[mi][j] *= xv[mi][j];   // next power, fp32
            }
        }

        if (g < 7) {
#pragma unroll
            for (int mi = 0; mi < 2; ++mi)
#pragma unroll
                for (int j = 0; j < 8; ++j) { xv[mi][j] = xn[mi][j]; pw[mi][j] = xn[mi][j]; }
        }
    }

    // ---- epilogue (verified R2/R3): pair (sum_p, sum_q) frags, bias, divide, float4 store ----
#pragma unroll
    for (int j = 0; j < 2; ++j) {
        const int o = (nt * 2 + j) * 16 + col;
        const float bias = bp[o];
#pragma unroll
        for (int mi = 0; mi < 2; ++mi) {
            f32x4 sp = acc[mi][2 * j];
            f32x4 sq = acc[mi][2 * j + 1];
            const int mrow = m0 + mi * 16 + quad * 4;  // 4 consecutive hw, same image
            const int b2  = mrow / HW3;
            const int hw2 = mrow - b2 * HW3;
            float4 v;
            v.x = (sp[0] + bias) / (1.0f + fabsf(sq[0]));
            v.y = (sp[1] + bias) / (1.0f + fabsf(sq[1]));
            v.z = (sp[2] + bias) / (1.0f + fabsf(sq[2]));
            v.w = (sp[3] + bias) / (1.0f + fabsf(sq[3]));
            *(float4*)&out[((size_t)b2 * 256 + o) * HW3 + hw2] = v;
        }
    }
}

extern "C" void kernel_launch(void* const* d_in, const int* in_sizes, int n_in,
                              void* d_out, int out_size, void* d_ws, size_t ws_size,
                              hipStream_t stream) {
    const float* x  = (const float*)d_in[0];
    const float* Wp = (const float*)d_in[1];
    const float* bp = (const float*)d_in[2];
    const float* Wq = (const float*)d_in[3];
    float* out = (float*)d_out;
    unsigned short* Whi = (unsigned short*)d_ws;              // 1.31 MB
    unsigned short* Wlo = Whi + WPLANE;                        // +1.31 MB

    pack_w_kernel<<<WPLANE / 256, 256, 0, stream>>>(Wp, Wq, Whi, Wlo);
    kanv_gemm<<<(MTOT / 128) * 8, 256, 0, stream>>>(x, Whi, Wlo, bp, out);
}